// Round 4
// baseline (326.779 us; speedup 1.0000x reference)
//
#include <hip/hip_runtime.h>

#define P 256
#define C 28
#define NPIX (P * P)            // 65536
#define NB 32                   // batch
#define Q 7                     // float4s per pixel (28 floats)
#define BLK 448                 // 64 pixels * 7 float4s = 7 waves
#define PIX_PER_BLK 64
#define F4_PER_IMG (NPIX * Q)   // 458752
#define IMG_GROUPS 2
#define IMGS_PER_GRP (NB / IMG_GROUPS)   // 16
#define PIX_BLOCKS (NPIX / PIX_PER_BLK)  // 1024

// Fused, double-buffered:
//  - grid = 2048 blocks = 2 image-groups x 1024 pixel-slices. Each block owns
//    64 pixels (all 28 channels) for 16 images -> halves R3's serial loop.
//  - shifted mask m[i,j,ch] = bk[(i-ch)&255, j, ch] gathered once per thread
//    into a register float4 (scalar loads, L2/L3-hot, ~6 us aggregate).
//  - x read fully coalesced as float4, register-prefetched across the barrier.
//  - double-buffered LDS: ONE __syncthreads per image-iteration (reduce of
//    iter b reads s[b&1] while iter b+1 writes s[(b+1)&1]; the next barrier
//    fences the WAR on s[b&1]).
__global__ __launch_bounds__(BLK) void codednet_fused2_kernel(
    const float4* __restrict__ x4, const float* __restrict__ bk,
    float* __restrict__ out) {
    __shared__ float s[2][BLK];
    const int t = threadIdx.x;
    const int pixslice = blockIdx.x & (PIX_BLOCKS - 1);
    const int b0 = (blockIdx.x >> 10) * IMGS_PER_GRP;   // first image
    const int p = t / Q;                    // local pixel 0..63
    const int k = t - p * Q;                // f4 slot 0..6
    const int pixbase = pixslice * PIX_PER_BLK;
    const int pixel = pixbase + p;
    const int i = pixel >> 8;
    const int j = pixel & (P - 1);
    const int ch0 = 4 * k;

    // First x load issued before the (dependent-chain-long) mask gather.
    const float4* xp = x4 + (size_t)b0 * F4_PER_IMG + (size_t)pixslice * BLK + t;
    float4 a = xp[0];

    float4 m;
    m.x = bk[(((i - (ch0 + 0)) & (P - 1)) * P + j) * C + (ch0 + 0)];
    m.y = bk[(((i - (ch0 + 1)) & (P - 1)) * P + j) * C + (ch0 + 1)];
    m.z = bk[(((i - (ch0 + 2)) & (P - 1)) * P + j) * C + (ch0 + 2)];
    m.w = bk[(((i - (ch0 + 3)) & (P - 1)) * P + j) * C + (ch0 + 3)];

#pragma unroll 2
    for (int b = 0; b < IMGS_PER_GRP; ++b) {
        float4 nxt = a;
        if (b + 1 < IMGS_PER_GRP) nxt = xp[(size_t)(b + 1) * F4_PER_IMG];
        s[b & 1][t] = a.x * m.x + a.y * m.y + a.z * m.z + a.w * m.w;
        __syncthreads();
        if (t < PIX_PER_BLK) {
            const float* q = s[b & 1] + t * Q;
            out[(size_t)(b0 + b) * NPIX + pixbase + t] =
                ((q[0] + q[1]) + (q[2] + q[3])) + ((q[4] + q[5]) + q[6]);
        }
        a = nxt;
    }
}

extern "C" void kernel_launch(void* const* d_in, const int* in_sizes, int n_in,
                              void* d_out, int out_size, void* d_ws, size_t ws_size,
                              hipStream_t stream) {
    const float* x  = (const float*)d_in[0];
    const float* bk = (const float*)d_in[1];
    float* out = (float*)d_out;
    (void)d_ws; (void)ws_size; (void)in_sizes; (void)n_in; (void)out_size;

    codednet_fused2_kernel<<<IMG_GROUPS * PIX_BLOCKS, BLK, 0, stream>>>(
        (const float4*)x, bk, out);
}